// Round 1
// baseline (284.414 us; speedup 1.0000x reference)
//
#include <hip/hip_runtime.h>
#include <hip/hip_bf16.h>

typedef __attribute__((ext_vector_type(8))) short bf16x8;
typedef __attribute__((ext_vector_type(4))) float f32x4;

#define MARGIN 0.1f

__device__ __forceinline__ unsigned short f2bf(float f) {
    unsigned int u = __builtin_bit_cast(unsigned int, f);
    u += 0x7fff + ((u >> 16) & 1);   // round-to-nearest-even (inputs are finite)
    return (unsigned short)(u >> 16);
}

// Kernel 1: L2-normalize rows of inputs -> bf16 x; neg[b] = dot(x, emb[target[b]])
__global__ __launch_bounds__(256) void prep_kernel(
    const float* __restrict__ inputs, const float* __restrict__ emb,
    const int* __restrict__ target, unsigned short* __restrict__ x_bf,
    float* __restrict__ neg)
{
    const int b = blockIdx.x;
    const int t = threadIdx.x;                    // 256 threads, 2 elems each
    const float2 v = *reinterpret_cast<const float2*>(inputs + (size_t)b * 512 + t * 2);
    const int tgt = target[b];
    const float2 e = *reinterpret_cast<const float2*>(emb + (size_t)tgt * 512 + t * 2);
    float ss = v.x * v.x + v.y * v.y;
    float de = v.x * e.x + v.y * e.y;
    #pragma unroll
    for (int off = 32; off; off >>= 1) {
        ss += __shfl_down(ss, off);
        de += __shfl_down(de, off);
    }
    __shared__ float s_ss[4], s_de[4];
    const int wid = t >> 6, lane = t & 63;
    if (lane == 0) { s_ss[wid] = ss; s_de[wid] = de; }
    __syncthreads();
    const float tss = s_ss[0] + s_ss[1] + s_ss[2] + s_ss[3];
    const float tde = s_de[0] + s_de[1] + s_de[2] + s_de[3];
    const float inv = 1.0f / fmaxf(sqrtf(tss), 1e-12f);
    const unsigned int h0 = f2bf(v.x * inv), h1 = f2bf(v.y * inv);
    *reinterpret_cast<unsigned int*>(x_bf + (size_t)b * 512 + t * 2) = h0 | (h1 << 16);
    if (t == 0) neg[b] = tde * inv;
}

// Kernel 2: per-block 128-row emb tile (f32->bf16 in LDS, full K=512), loop all
// 1024 x-rows in 4 chunks of 256. 8 waves (4M x 2N), 64x64 wave tile, fused
// relu-margin-sum epilogue. One partial per block.
__global__ __launch_bounds__(512, 2) void gemm_loss_kernel(
    const unsigned short* __restrict__ x_bf, const float* __restrict__ emb,
    const float* __restrict__ neg, float* __restrict__ partials)
{
    __shared__ short btile[128 * 512];            // 128 KB, XOR-swizzled bf16
    char* lds = reinterpret_cast<char*>(btile);
    const int t = threadIdx.x;                    // 512 threads
    const int v0 = blockIdx.x * 128;

    // ---- stage emb tile: 128 rows x 512 cols f32 -> bf16 LDS ----
    #pragma unroll
    for (int p = 0; p < 32; ++p) {
        const int i = p * 512 + t;                // 0..16383
        const int row = i >> 7;                   // 0..127
        const int c4 = i & 127;                   // float4 column
        const float4 f = *reinterpret_cast<const float4*>(
            emb + (size_t)(v0 + row) * 512 + c4 * 4);
        const int byte = (row * 1024 + c4 * 8) ^ ((row & 7) << 4);
        ushort4 h;
        h.x = f2bf(f.x); h.y = f2bf(f.y); h.z = f2bf(f.z); h.w = f2bf(f.w);
        *reinterpret_cast<ushort4*>(lds + byte) = h;
    }
    __syncthreads();

    const int wid = t >> 6, lane = t & 63;
    const int wm = wid >> 1;                      // 0..3
    const int wn = wid & 1;                       // 0..1
    const int lrow = lane & 15;
    const int lk = (lane >> 4) * 8;               // k sub-offset 0/8/16/24

    float sum = 0.0f;

    #pragma unroll 1
    for (int mc = 0; mc < 4; ++mc) {
        const int mbase = mc * 256 + wm * 64;
        f32x4 acc[4][4];
        #pragma unroll
        for (int i = 0; i < 4; ++i)
            #pragma unroll
            for (int j = 0; j < 4; ++j) acc[i][j] = (f32x4)(0.0f);

        const unsigned short* aptr = x_bf + (size_t)(mbase + lrow) * 512 + lk;

        #pragma unroll 4
        for (int kk = 0; kk < 16; ++kk) {
            const int k = kk * 32;
            bf16x8 a[4], bfr[4];
            #pragma unroll
            for (int mf = 0; mf < 4; ++mf)
                a[mf] = *reinterpret_cast<const bf16x8*>(aptr + mf * (16 * 512) + k);
            #pragma unroll
            for (int nf = 0; nf < 4; ++nf) {
                const int vloc = wn * 64 + nf * 16 + lrow;
                const int byte = (vloc * 1024 + (k + lk) * 2) ^ ((vloc & 7) << 4);
                bfr[nf] = *reinterpret_cast<const bf16x8*>(lds + byte);
            }
            #pragma unroll
            for (int mf = 0; mf < 4; ++mf)
                #pragma unroll
                for (int nf = 0; nf < 4; ++nf)
                    acc[mf][nf] = __builtin_amdgcn_mfma_f32_16x16x32_bf16(
                        a[mf], bfr[nf], acc[mf][nf], 0, 0, 0);
        }

        // ---- fused epilogue: relu(margin + dot - neg[m]) summed ----
        #pragma unroll
        for (int mf = 0; mf < 4; ++mf) {
            const int mr = mbase + mf * 16 + (lane >> 4) * 4;
            #pragma unroll
            for (int j = 0; j < 4; ++j) {
                const float nv = neg[mr + j];
                #pragma unroll
                for (int nf = 0; nf < 4; ++nf)
                    sum += fmaxf(MARGIN + acc[mf][nf][j] - nv, 0.0f);
            }
        }
    }

    // ---- block reduction (reuse LDS after barrier) ----
    __syncthreads();
    #pragma unroll
    for (int off = 32; off; off >>= 1) sum += __shfl_down(sum, off);
    float* red = reinterpret_cast<float*>(lds);
    if (lane == 0) red[wid] = sum;
    __syncthreads();
    if (t == 0) {
        float tot = 0.f;
        #pragma unroll
        for (int w = 0; w < 8; ++w) tot += red[w];
        partials[blockIdx.x] = tot;
    }
}

// Kernel 3: deterministic final reduction of 1000 block partials, mean over B.
__global__ __launch_bounds__(256) void reduce_kernel(
    const float* __restrict__ partials, float* __restrict__ out)
{
    float s = 0.f;
    for (int i = threadIdx.x; i < 1000; i += 256) s += partials[i];
    #pragma unroll
    for (int off = 32; off; off >>= 1) s += __shfl_down(s, off);
    __shared__ float red[4];
    const int wid = threadIdx.x >> 6, lane = threadIdx.x & 63;
    if (lane == 0) red[wid] = s;
    __syncthreads();
    if (threadIdx.x == 0)
        out[0] = (red[0] + red[1] + red[2] + red[3]) * (1.0f / 1024.0f);
}

extern "C" void kernel_launch(void* const* d_in, const int* in_sizes, int n_in,
                              void* d_out, int out_size, void* d_ws, size_t ws_size,
                              hipStream_t stream)
{
    const float* inputs = (const float*)d_in[0];
    const float* emb    = (const float*)d_in[1];
    const int*   target = (const int*)d_in[2];
    float* out = (float*)d_out;
    char*  ws  = (char*)d_ws;

    unsigned short* x_bf  = (unsigned short*)ws;                    // 1 MB
    float*          neg   = (float*)(ws + (1 << 20));               // 4 KB
    float*          parts = (float*)(ws + (1 << 20) + (1 << 14));   // 4 KB

    prep_kernel<<<1024, 256, 0, stream>>>(inputs, emb, target, x_bf, neg);
    gemm_loss_kernel<<<1000, 512, 0, stream>>>(x_bf, emb, neg, parts);
    reduce_kernel<<<1, 256, 0, stream>>>(parts, out);
}